// Round 2
// baseline (299.513 us; speedup 1.0000x reference)
//
#include <hip/hip_runtime.h>
#include <hip/hip_bf16.h>

#define H    128
#define NB   256
#define NRES 262144

typedef __attribute__((ext_vector_type(4))) float f32x4;
typedef __attribute__((ext_vector_type(8))) short short8;

__device__ __forceinline__ short bf16cvt(float f) {
  unsigned u = __builtin_bit_cast(unsigned, f);
  unsigned r = (u + 0x7fffu + ((u >> 16) & 1u)) >> 16;  // RNE
  return (short)r;
}

__device__ __forceinline__ short8 pack_bf16x8(f32x4 x, f32x4 y) {
  short8 v;
  v[0] = bf16cvt(x[0]); v[1] = bf16cvt(x[1]);
  v[2] = bf16cvt(x[2]); v[3] = bf16cvt(x[3]);
  v[4] = bf16cvt(y[0]); v[5] = bf16cvt(y[1]);
  v[6] = bf16cvt(y[2]); v[7] = bf16cvt(y[3]);
  return v;
}

__device__ __forceinline__ int lower_bound_i(const int* __restrict__ a, int n, int v) {
  int lo = 0, hi = n;
  while (lo < hi) { int mid = (lo + hi) >> 1; if (a[mid] < v) lo = mid + 1; else hi = mid; }
  return lo;
}

// ---------------- kernel 1: q = relu(mol Wq^T + bq); s2[b] = q[b] . wm2 ----------------
__global__ __launch_bounds__(128) void qkern(
    const float* __restrict__ mol, const float* __restrict__ Wq,
    const float* __restrict__ bq, const float* __restrict__ Wm,
    float* __restrict__ out, float* __restrict__ s2) {
  int b = blockIdx.x, h = threadIdx.x;
  const float* mrow = mol + b * H;
  const float* wrow = Wq + h * H;
  float acc = bq[h];
#pragma unroll 8
  for (int j = 0; j < H; ++j) acc = fmaf(mrow[j], wrow[j], acc);
  float q = fmaxf(acc, 0.f);
  out[NB * H + b * H + h] = q;  // q output (second tuple element)
  out[b * H + h] = 0.f;         // zero o output region (atomics target)
  float p = q * Wm[H + h];
#pragma unroll
  for (int off = 32; off >= 1; off >>= 1) p += __shfl_xor(p, off);
  __shared__ float red[2];
  if ((threadIdx.x & 63) == 0) red[threadIdx.x >> 6] = p;
  __syncthreads();
  if (threadIdx.x == 0) s2[b] = red[0] + red[1];
}

// ---- shared helper: populate Wk bf16 fragments in LDS, lane-linear (conflict-free) ----
// frag f = ct*4+kk ; lane l holds B[k=(l>>4)*8+j][col=(l&15)] = Wk[ct*16+(l&15)][kk*32+(l>>4)*8+j]
__device__ __forceinline__ void fill_wk_frags(short* __restrict__ bfrag,
                                              const float* __restrict__ Wk, int tid) {
  for (int slot = tid; slot < 32 * 64; slot += 256) {
    int f = slot >> 6, l = slot & 63;
    int ct = f >> 2, kk = f & 3;
    const float* src = Wk + (ct * 16 + (l & 15)) * H + kk * 32 + (l >> 4) * 8;
    f32x4 x = *(const f32x4*)src;
    f32x4 y = *(const f32x4*)(src + 4);
    *(short8*)&bfrag[slot * 8] = pack_bf16x8(x, y);
  }
}

// ---------------- kernel 2: score[n] = relu(prot Wk^T + bk) . wm1 + s2[batch[n]] ----------------
__global__ __launch_bounds__(256) void scorekern(
    const float* __restrict__ prot, const int* __restrict__ batch,
    const float* __restrict__ Wk, const float* __restrict__ bk,
    const float* __restrict__ Wm, const float* __restrict__ s2,
    float* __restrict__ score) {
  __shared__ short bfrag[32 * 64 * 8];
  int tid = threadIdx.x;
  fill_wk_frags(bfrag, Wk, tid);
  __syncthreads();
  int w = tid >> 6, l = tid & 63;
  int cg = l & 15, kg = l >> 4;
  float wm1v[8], bkv[8];
#pragma unroll
  for (int ct = 0; ct < 8; ++ct) { wm1v[ct] = Wm[ct * 16 + cg]; bkv[ct] = bk[ct * 16 + cg]; }
  int gw = blockIdx.x * 4 + w;
  int nw = gridDim.x * 4;
  for (int t = gw; t < NRES / 16; t += nw) {
    int r0 = t * 16;
    const float* pbase = prot + (r0 + cg) * H + kg * 8;
    short8 a[4];
#pragma unroll
    for (int kk = 0; kk < 4; ++kk) {
      f32x4 x = *(const f32x4*)(pbase + kk * 32);
      f32x4 y = *(const f32x4*)(pbase + kk * 32 + 4);
      a[kk] = pack_bf16x8(x, y);
    }
    f32x4 acc[8];
#pragma unroll
    for (int ct = 0; ct < 8; ++ct) acc[ct] = (f32x4){0.f, 0.f, 0.f, 0.f};
#pragma unroll
    for (int ct = 0; ct < 8; ++ct)
#pragma unroll
      for (int kk = 0; kk < 4; ++kk) {
        short8 bf = *(const short8*)&bfrag[((ct * 4 + kk) * 64 + l) * 8];
        acc[ct] = __builtin_amdgcn_mfma_f32_16x16x32_bf16(a[kk], bf, acc[ct], 0, 0, 0);
      }
    float p0 = 0.f, p1 = 0.f, p2 = 0.f, p3 = 0.f;
#pragma unroll
    for (int ct = 0; ct < 8; ++ct) {
      p0 += fmaxf(acc[ct][0] + bkv[ct], 0.f) * wm1v[ct];
      p1 += fmaxf(acc[ct][1] + bkv[ct], 0.f) * wm1v[ct];
      p2 += fmaxf(acc[ct][2] + bkv[ct], 0.f) * wm1v[ct];
      p3 += fmaxf(acc[ct][3] + bkv[ct], 0.f) * wm1v[ct];
    }
#pragma unroll
    for (int off = 1; off < 16; off <<= 1) {
      p0 += __shfl_xor(p0, off); p1 += __shfl_xor(p1, off);
      p2 += __shfl_xor(p2, off); p3 += __shfl_xor(p3, off);
    }
    if (cg < 4) {
      int j = l & 3;
      float pv = (j == 0) ? p0 : (j == 1) ? p1 : (j == 2) ? p2 : p3;
      int n = r0 + kg * 4 + j;
      score[n] = pv + s2[batch[n]];
    }
  }
}

// ---------------- kernel 3: per-segment max + 1/sum(exp) ----------------
__global__ __launch_bounds__(256) void segred(
    const int* __restrict__ batch, const float* __restrict__ score,
    float* __restrict__ mval, float* __restrict__ dinv) {
  int b = blockIdx.x, tid = threadIdx.x;
  int start = lower_bound_i(batch, NRES, b);
  int end = lower_bound_i(batch, NRES, b + 1);
  float m = -3.0e38f;
  for (int i = start + tid; i < end; i += 256) m = fmaxf(m, score[i]);
#pragma unroll
  for (int off = 32; off >= 1; off >>= 1) m = fmaxf(m, __shfl_xor(m, off));
  __shared__ float red[4];
  if ((tid & 63) == 0) red[tid >> 6] = m;
  __syncthreads();
  m = fmaxf(fmaxf(red[0], red[1]), fmaxf(red[2], red[3]));
  float s = 0.f;
  for (int i = start + tid; i < end; i += 256) s += __expf(score[i] - m);
#pragma unroll
  for (int off = 32; off >= 1; off >>= 1) s += __shfl_xor(s, off);
  __shared__ float red2[4];
  if ((tid & 63) == 0) red2[tid >> 6] = s;
  __syncthreads();
  if (tid == 0) {
    s = red2[0] + red2[1] + red2[2] + red2[3];
    mval[b] = m;
    dinv[b] = (s > 0.f) ? 1.f / s : 0.f;
  }
}

// ---------------- kernel 4: o[b] = sum_n attn[n] * relu(prot Wk^T + bk)[n] ----------------
#define SB 8
__global__ __launch_bounds__(256) void outkern(
    const float* __restrict__ prot, const int* __restrict__ batch,
    const float* __restrict__ Wk, const float* __restrict__ bk,
    const float* __restrict__ score, const float* __restrict__ mval,
    const float* __restrict__ dinv, float* __restrict__ out) {
  __shared__ short bfrag[32 * 64 * 8];
  __shared__ float o_sh[H];
  int tid = threadIdx.x;
  int b = blockIdx.x >> 3, sub = blockIdx.x & 7;
  fill_wk_frags(bfrag, Wk, tid);
  if (tid < H) o_sh[tid] = 0.f;
  __syncthreads();
  int start = lower_bound_i(batch, NRES, b);
  int end = lower_bound_i(batch, NRES, b + 1);
  float m = mval[b], inv_d = dinv[b];
  int w = tid >> 6, l = tid & 63;
  int cg = l & 15, kg = l >> 4;
  float bkv[8];
#pragma unroll
  for (int ct = 0; ct < 8; ++ct) bkv[ct] = bk[ct * 16 + cg];
  float op[8] = {0.f, 0.f, 0.f, 0.f, 0.f, 0.f, 0.f, 0.f};
  int ntiles = (end - start + 15) >> 4;
  for (int t = sub * 4 + w; t < ntiles; t += SB * 4) {
    int r0 = start + t * 16;
    int arow = min(r0 + cg, NRES - 1);
    const float* pbase = prot + arow * H + kg * 8;
    short8 a[4];
#pragma unroll
    for (int kk = 0; kk < 4; ++kk) {
      f32x4 x = *(const f32x4*)(pbase + kk * 32);
      f32x4 y = *(const f32x4*)(pbase + kk * 32 + 4);
      a[kk] = pack_bf16x8(x, y);
    }
    f32x4 acc[8];
#pragma unroll
    for (int ct = 0; ct < 8; ++ct) acc[ct] = (f32x4){0.f, 0.f, 0.f, 0.f};
#pragma unroll
    for (int ct = 0; ct < 8; ++ct)
#pragma unroll
      for (int kk = 0; kk < 4; ++kk) {
        short8 bf = *(const short8*)&bfrag[((ct * 4 + kk) * 64 + l) * 8];
        acc[ct] = __builtin_amdgcn_mfma_f32_16x16x32_bf16(a[kk], bf, acc[ct], 0, 0, 0);
      }
    float at0, at1, at2, at3;
    {
      int r = r0 + kg * 4;
      at0 = (r + 0 < end) ? __expf(score[r + 0] - m) * inv_d : 0.f;
      at1 = (r + 1 < end) ? __expf(score[r + 1] - m) * inv_d : 0.f;
      at2 = (r + 2 < end) ? __expf(score[r + 2] - m) * inv_d : 0.f;
      at3 = (r + 3 < end) ? __expf(score[r + 3] - m) * inv_d : 0.f;
    }
#pragma unroll
    for (int ct = 0; ct < 8; ++ct) {
      op[ct] += at0 * fmaxf(acc[ct][0] + bkv[ct], 0.f);
      op[ct] += at1 * fmaxf(acc[ct][1] + bkv[ct], 0.f);
      op[ct] += at2 * fmaxf(acc[ct][2] + bkv[ct], 0.f);
      op[ct] += at3 * fmaxf(acc[ct][3] + bkv[ct], 0.f);
    }
  }
#pragma unroll
  for (int ct = 0; ct < 8; ++ct) {
    op[ct] += __shfl_xor(op[ct], 16);
    op[ct] += __shfl_xor(op[ct], 32);
  }
  if (l < 16) {
#pragma unroll
    for (int ct = 0; ct < 8; ++ct) atomicAdd(&o_sh[ct * 16 + l], op[ct]);
  }
  __syncthreads();
  if (tid < H) atomicAdd(&out[b * H + tid], o_sh[tid]);
}

extern "C" void kernel_launch(void* const* d_in, const int* in_sizes, int n_in,
                              void* d_out, int out_size, void* d_ws, size_t ws_size,
                              hipStream_t stream) {
  const float* mol   = (const float*)d_in[0];
  const float* prot  = (const float*)d_in[1];
  const int*   batch = (const int*)d_in[2];
  const float* Wq    = (const float*)d_in[3];
  const float* bq    = (const float*)d_in[4];
  const float* Wk    = (const float*)d_in[5];
  const float* bk    = (const float*)d_in[6];
  const float* Wm    = (const float*)d_in[7];
  float* out = (float*)d_out;

  float* score = (float*)d_ws;       // NRES floats
  float* s2    = score + NRES;       // NB floats
  float* mval  = s2 + NB;            // NB floats
  float* dinv  = mval + NB;          // NB floats

  hipLaunchKernelGGL(qkern, dim3(NB), dim3(128), 0, stream, mol, Wq, bq, Wm, out, s2);
  hipLaunchKernelGGL(scorekern, dim3(2048), dim3(256), 0, stream, prot, batch, Wk, bk, Wm, s2, score);
  hipLaunchKernelGGL(segred, dim3(NB), dim3(256), 0, stream, batch, score, mval, dinv);
  hipLaunchKernelGGL(outkern, dim3(NB * SB), dim3(256), 0, stream, prot, batch, Wk, bk, score, mval, dinv, out);
}

// Round 3
// 242.796 us; speedup vs baseline: 1.2336x; 1.2336x over previous
//
#include <hip/hip_runtime.h>
#include <hip/hip_bf16.h>

#define H      128
#define NB     256
#define NRES   262144
#define CHUNK  128
#define NCHUNK (NRES / CHUNK)   // 2048
#define PIECES 64               // partial slots per segment (segment spans <= ~11 chunks)
#define REC    136              // floats per partial record: m, s, pad[6], v[128]

typedef __attribute__((ext_vector_type(4))) float f32x4;
typedef __attribute__((ext_vector_type(8))) short short8;

__device__ __forceinline__ short bf16cvt(float f) {
  unsigned u = __builtin_bit_cast(unsigned, f);
  unsigned r = (u + 0x7fffu + ((u >> 16) & 1u)) >> 16;  // RNE
  return (short)r;
}

__device__ __forceinline__ float bf16tof(unsigned short u) {
  unsigned v = ((unsigned)u) << 16;
  return __builtin_bit_cast(float, v);
}

__device__ __forceinline__ short8 pack_bf16x8(f32x4 x, f32x4 y) {
  short8 v;
  v[0] = bf16cvt(x[0]); v[1] = bf16cvt(x[1]);
  v[2] = bf16cvt(x[2]); v[3] = bf16cvt(x[3]);
  v[4] = bf16cvt(y[0]); v[5] = bf16cvt(y[1]);
  v[6] = bf16cvt(y[2]); v[7] = bf16cvt(y[3]);
  return v;
}

__device__ __forceinline__ int lower_bound_i(const int* __restrict__ a, int n, int v) {
  int lo = 0, hi = n;
  while (lo < hi) { int mid = (lo + hi) >> 1; if (a[mid] < v) lo = mid + 1; else hi = mid; }
  return lo;
}

// ------------- kernel 1 (fused): q = relu(mol Wq^T + bq)  +  pack Wk bf16 frags -------------
// blocks [0,NB): q rows. blocks [NB, NB+8): pack 2048 fragment slots (8 shorts each).
// frag slot = f*64+l ; f = ct*4+kk ; lane l holds B[k=(l>>4)*8+j][col=(l&15)]
//            = Wk[ct*16+(l&15)][kk*32+(l>>4)*8+j]
__global__ __launch_bounds__(256) void prep(
    const float* __restrict__ mol, const float* __restrict__ Wq,
    const float* __restrict__ bq, const float* __restrict__ Wk,
    float* __restrict__ out, short* __restrict__ wkp) {
  int bid = blockIdx.x, tid = threadIdx.x;
  if (bid < NB) {
    if (tid < H) {
      const float* mrow = mol + bid * H;
      const float* wrow = Wq + tid * H;
      float acc = bq[tid];
#pragma unroll 8
      for (int j = 0; j < H; ++j) acc = fmaf(mrow[j], wrow[j], acc);
      out[NB * H + bid * H + tid] = fmaxf(acc, 0.f);  // q (exact f32)
    }
  } else {
    int slot = (bid - NB) * 256 + tid;  // 0..2047
    int f = slot >> 6, l = slot & 63;
    int ct = f >> 2, kk = f & 3;
    const float* src = Wk + (ct * 16 + (l & 15)) * H + kk * 32 + (l >> 4) * 8;
    f32x4 x = *(const f32x4*)src;
    f32x4 y = *(const f32x4*)(src + 4);
    *(short8*)&wkp[slot * 8] = pack_bf16x8(x, y);
  }
}

// ------------- kernel 2: per-128-row chunk: k = relu(prot Wk^T + bk) via MFMA,
//               score = k . wm1  (s2[batch] dropped: constant per segment, cancels in softmax),
//               then per-segment-piece flash partials (m, sum e, sum e*k) -------------
__global__ __launch_bounds__(256) void chunkkern(
    const float* __restrict__ prot, const int* __restrict__ batch,
    const short* __restrict__ wkp, const float* __restrict__ bk,
    const float* __restrict__ Wm, float* __restrict__ part) {
  __shared__ short bfrag[2048 * 8];                 // 32 KB packed Wk frags
  __shared__ unsigned short k_sh[CHUNK * 132];      // 33 KB, padded stride 132
  __shared__ float score_sh[CHUNK];
  __shared__ float e_sh[CHUNK];
  __shared__ float vhalf[H];
  __shared__ int   batch_sh[CHUNK];
  __shared__ float red[4], red2[4];

  int tid = threadIdx.x;
  int c0row = blockIdx.x * CHUNK;

  // stage packed frags (32 KB, coalesced 16B/thread)
  for (int i = tid; i < 2048; i += 256)
    *(short8*)&bfrag[i * 8] = *(const short8*)&wkp[i * 8];
  if (tid < CHUNK) batch_sh[tid] = batch[c0row + tid];
  __syncthreads();

  int w = tid >> 6, l = tid & 63;
  int cg = l & 15, kg = l >> 4;
  float wm1v[8], bkv[8];
#pragma unroll
  for (int ct = 0; ct < 8; ++ct) { wm1v[ct] = Wm[ct * 16 + cg]; bkv[ct] = bk[ct * 16 + cg]; }

  // each wave computes rows [w*32, w*32+32) as two 16-row MFMA tiles
#pragma unroll
  for (int tile = 0; tile < 2; ++tile) {
    int rbase = w * 32 + tile * 16;
    const float* pbase = prot + (c0row + rbase + cg) * H + kg * 8;
    short8 a[4];
#pragma unroll
    for (int kk = 0; kk < 4; ++kk) {
      f32x4 x = *(const f32x4*)(pbase + kk * 32);
      f32x4 y = *(const f32x4*)(pbase + kk * 32 + 4);
      a[kk] = pack_bf16x8(x, y);
    }
    f32x4 acc[8];
#pragma unroll
    for (int ct = 0; ct < 8; ++ct) acc[ct] = (f32x4){0.f, 0.f, 0.f, 0.f};
#pragma unroll
    for (int ct = 0; ct < 8; ++ct)
#pragma unroll
      for (int kk = 0; kk < 4; ++kk) {
        short8 bf = *(const short8*)&bfrag[((ct * 4 + kk) * 64 + l) * 8];
        acc[ct] = __builtin_amdgcn_mfma_f32_16x16x32_bf16(a[kk], bf, acc[ct], 0, 0, 0);
      }
    // epilogue: relu+bias, store k to LDS, accumulate score dot
    float p0 = 0.f, p1 = 0.f, p2 = 0.f, p3 = 0.f;
    int row0 = rbase + kg * 4;
#pragma unroll
    for (int ct = 0; ct < 8; ++ct) {
      float v0 = fmaxf(acc[ct][0] + bkv[ct], 0.f);
      float v1 = fmaxf(acc[ct][1] + bkv[ct], 0.f);
      float v2 = fmaxf(acc[ct][2] + bkv[ct], 0.f);
      float v3 = fmaxf(acc[ct][3] + bkv[ct], 0.f);
      p0 += v0 * wm1v[ct]; p1 += v1 * wm1v[ct];
      p2 += v2 * wm1v[ct]; p3 += v3 * wm1v[ct];
      int colb = ct * 16 + cg;
      k_sh[(row0 + 0) * 132 + colb] = (unsigned short)bf16cvt(v0);
      k_sh[(row0 + 1) * 132 + colb] = (unsigned short)bf16cvt(v1);
      k_sh[(row0 + 2) * 132 + colb] = (unsigned short)bf16cvt(v2);
      k_sh[(row0 + 3) * 132 + colb] = (unsigned short)bf16cvt(v3);
    }
#pragma unroll
    for (int off = 1; off < 16; off <<= 1) {
      p0 += __shfl_xor(p0, off); p1 += __shfl_xor(p1, off);
      p2 += __shfl_xor(p2, off); p3 += __shfl_xor(p3, off);
    }
    if (cg < 4) {
      int j = l & 3;
      float pv = (j == 0) ? p0 : (j == 1) ? p1 : (j == 2) ? p2 : p3;
      score_sh[rbase + kg * 4 + j] = pv;
    }
  }
  __syncthreads();

  // -------- per-segment pieces within this chunk (flash partials) --------
  int b0 = batch_sh[0], b1 = batch_sh[CHUNK - 1];
  int slot = blockIdx.x & (PIECES - 1);
  for (int b = b0; b <= b1; ++b) {
    int lo, hi;
    { int L = 0, R = CHUNK; while (L < R) { int M = (L + R) >> 1; if (batch_sh[M] < b) L = M + 1; else R = M; } lo = L; }
    { int L = 0, R = CHUNK; while (L < R) { int M = (L + R) >> 1; if (batch_sh[M] <= b) L = M + 1; else R = M; } hi = L; }
    if (hi > lo) {  // uniform branch (all threads computed same lo/hi)
      // piece max
      float x = (tid < CHUNK && tid >= lo && tid < hi) ? score_sh[tid] : -3.0e38f;
#pragma unroll
      for (int off = 32; off >= 1; off >>= 1) x = fmaxf(x, __shfl_xor(x, off));
      if (l == 0) red[w] = x;
      __syncthreads();
      float m_loc = fmaxf(fmaxf(red[0], red[1]), fmaxf(red[2], red[3]));
      // e and piece sum
      float e = 0.f;
      if (tid < CHUNK && tid >= lo && tid < hi) { e = __expf(score_sh[tid] - m_loc); e_sh[tid] = e; }
      float s = e;
#pragma unroll
      for (int off = 32; off >= 1; off >>= 1) s += __shfl_xor(s, off);
      if (l == 0) red2[w] = s;
      __syncthreads();  // publishes e_sh and red2
      float s_loc = red2[0] + red2[1] + red2[2] + red2[3];
      // weighted k sum: 2 threads per column, split rows
      int c = tid & 127, half = tid >> 7;
      float acc = 0.f;
      for (int r = lo + half; r < hi; r += 2)
        acc += e_sh[r] * bf16tof(k_sh[r * 132 + c]);
      if (half) vhalf[c] = acc;
      __syncthreads();
      float* pp = part + ((size_t)b * PIECES + slot) * REC;
      if (!half) pp[8 + c] = acc + vhalf[c];
      if (tid == 0) { pp[0] = m_loc; pp[1] = s_loc; }
      __syncthreads();  // protect red/e_sh/vhalf for next piece
    }
  }
}

// ------------- kernel 3: merge pieces per segment (exact flash merge), write o -------------
__global__ __launch_bounds__(128) void combine(
    const int* __restrict__ batch, const float* __restrict__ part,
    float* __restrict__ out) {
  int b = blockIdx.x, c = threadIdx.x;
  int start = lower_bound_i(batch, NRES, b);
  int end = lower_bound_i(batch, NRES, b + 1);
  if (end <= start) { out[b * H + c] = 0.f; return; }
  int c0 = start >> 7, c1 = (end - 1) >> 7;  // chunks intersecting segment b (all wrote a piece)
  float m = -3.0e38f;
  for (int ch = c0; ch <= c1; ++ch)
    m = fmaxf(m, part[((size_t)b * PIECES + (ch & (PIECES - 1))) * REC]);
  float denom = 0.f, v = 0.f;
  for (int ch = c0; ch <= c1; ++ch) {
    const float* pp = part + ((size_t)b * PIECES + (ch & (PIECES - 1))) * REC;
    float wgt = __expf(pp[0] - m);
    denom += pp[1] * wgt;
    v += pp[8 + c] * wgt;
  }
  out[b * H + c] = (denom > 0.f) ? v / denom : 0.f;
}

extern "C" void kernel_launch(void* const* d_in, const int* in_sizes, int n_in,
                              void* d_out, int out_size, void* d_ws, size_t ws_size,
                              hipStream_t stream) {
  const float* mol   = (const float*)d_in[0];
  const float* prot  = (const float*)d_in[1];
  const int*   batch = (const int*)d_in[2];
  const float* Wq    = (const float*)d_in[3];
  const float* bq    = (const float*)d_in[4];
  const float* Wk    = (const float*)d_in[5];
  const float* bk    = (const float*)d_in[6];
  const float* Wm    = (const float*)d_in[7];
  float* out = (float*)d_out;

  short* wkp  = (short*)d_ws;                          // 2048*8 shorts = 32 KB
  float* part = (float*)((char*)d_ws + 32768);         // NB*PIECES*REC floats ≈ 8.9 MB

  hipLaunchKernelGGL(prep, dim3(NB + 8), dim3(256), 0, stream, mol, Wq, bq, Wk, out, wkp);
  hipLaunchKernelGGL(chunkkern, dim3(NCHUNK), dim3(256), 0, stream, prot, batch, wkp, bk, Wm, part);
  hipLaunchKernelGGL(combine, dim3(NB), dim3(128), 0, stream, batch, part, out);
}